// Round 2
// baseline (125.371 us; speedup 1.0000x reference)
//
#include <hip/hip_runtime.h>

// Problem constants (from reference)
constexpr int B = 16384;
constexpr int T = 256;
constexpr int D = 8;
constexpr int F = 512;
constexpr int C = 16;
constexpr int L = 256;  // 2^D

struct FP { int fidx; float thr; };  // packed per-(t,d) node info, 8 B

// Kernel 1: per (t,d) argmax over F=512 feature weights, first-occurrence
// tie-break to match jnp.argmax. One wave per row; 4 rows per 256-thread block.
__global__ __launch_bounds__(256) void node_prep_kernel(
    const float* __restrict__ fw,      // (T, D, F)
    const float* __restrict__ thr,     // (T, D)
    FP* __restrict__ packed)           // (T*D)
{
    const int wave = threadIdx.x >> 6;
    const int lane = threadIdx.x & 63;
    const int row  = blockIdx.x * 4 + wave;          // [0, T*D)
    const float* base = fw + (size_t)row * F;

    float best = -INFINITY;
    int bidx = 0;
#pragma unroll
    for (int k = 0; k < F / 64; ++k) {
        const int idx = lane + k * 64;
        const float v = base[idx];
        // within-lane indices strictly increase, so '>' keeps first occurrence
        if (v > best) { best = v; bidx = idx; }
    }
    // 64-lane butterfly reduce; tie-break on smaller index (first occurrence)
#pragma unroll
    for (int off = 32; off >= 1; off >>= 1) {
        const float ov = __shfl_xor(best, off);
        const int   oi = __shfl_xor(bidx, off);
        if (ov > best || (ov == best && oi < bidx)) { best = ov; bidx = oi; }
    }
    if (lane == 0) {
        FP p;
        p.fidx = bidx;
        p.thr  = thr[row];
        packed[row] = p;
    }
}

// Kernel 2: 4 samples per block (4096 blocks, 256 threads).
// Phase 1: stage 4 x-rows (8 KB) in LDS via float4.
// Phase 2: thread t computes decision bytes for tree t for all 4 samples
//          (one 64 B node-table read amortized over 4 samples).
// Phase 3: wave w owns sample w. Lanes = 4 tree-slots x 16 channels.
//          Decision bytes come from uniform int4 LDS broadcasts (16 reads
//          per wave); 64 independent 4 B L2 gathers per lane; shuffle reduce.
__global__ __launch_bounds__(256) void forest_kernel(
    const float* __restrict__ x,          // (B, F)
    const FP* __restrict__ packed,        // (T*D)
    const float* __restrict__ responses,  // (T, L, C)
    float* __restrict__ out)              // (B, C)
{
    __shared__ float xrow[4][F];             // 8 KB
    __shared__ unsigned char sdec[4][T];     // 1 KB

    const int b0  = blockIdx.x * 4;
    const int tid = threadIdx.x;

    // Phase 1: 4 rows = 2048 floats = 512 float4; 2 per thread, coalesced.
    {
        const float4* xs = reinterpret_cast<const float4*>(x + (size_t)b0 * F);
        float4* xl = reinterpret_cast<float4*>(&xrow[0][0]);
        xl[tid]       = xs[tid];
        xl[tid + 256] = xs[tid + 256];
    }
    __syncthreads();

    // Phase 2: decisions for tree t = tid, samples 0..3.
    {
        const int2* p2 = reinterpret_cast<const int2*>(packed) + tid * D;
        int2 raw[D];
#pragma unroll
        for (int d = 0; d < D; ++d) raw[d] = p2[d];
        int dec0 = 0, dec1 = 0, dec2 = 0, dec3 = 0;
#pragma unroll
        for (int d = 0; d < D; ++d) {
            const int   f  = raw[d].x;
            const float th = __int_as_float(raw[d].y);
            const int   p  = 128 >> d;            // powers = 2^(D-1-d)
            dec0 |= (xrow[0][f] > th) ? p : 0;
            dec1 |= (xrow[1][f] > th) ? p : 0;
            dec2 |= (xrow[2][f] > th) ? p : 0;
            dec3 |= (xrow[3][f] > th) ? p : 0;
        }
        sdec[0][tid] = (unsigned char)dec0;
        sdec[1][tid] = (unsigned char)dec1;
        sdec[2][tid] = (unsigned char)dec2;
        sdec[3][tid] = (unsigned char)dec3;
    }
    __syncthreads();

    // Phase 3: wave w -> sample b0+w. lane = slot*16 + c.
    const int w    = tid >> 6;
    const int lane = tid & 63;
    const int slot = lane >> 4;
    const int c    = lane & 15;
    const int sh   = slot * 8;

    float accA = 0.0f, accB = 0.0f;
    const int4* pdec = reinterpret_cast<const int4*>(&sdec[w][0]);

#define GATH(ACC, WD, TB)                                                  \
    {                                                                      \
        const int dd = ((WD) >> sh) & 255;                                 \
        const int t  = (TB) + slot;                                        \
        ACC += responses[((size_t)(((t) << 8) | dd) << 4) + c];            \
    }

#pragma unroll
    for (int kk = 0; kk < 16; ++kk) {
        const int4 pd = pdec[kk];   // uniform address -> LDS broadcast
        GATH(accA, pd.x, kk * 16 + 0)
        GATH(accB, pd.y, kk * 16 + 4)
        GATH(accA, pd.z, kk * 16 + 8)
        GATH(accB, pd.w, kk * 16 + 12)
    }
#undef GATH

    float acc = accA + accB;
    // reduce the 4 tree-slots: lanes differing in bits 4 (16) and 5 (32)
    acc += __shfl_xor(acc, 16);
    acc += __shfl_xor(acc, 32);

    if (lane < 16) out[(size_t)(b0 + w) * C + lane] = acc * (1.0f / T);
}

extern "C" void kernel_launch(void* const* d_in, const int* in_sizes, int n_in,
                              void* d_out, int out_size, void* d_ws, size_t ws_size,
                              hipStream_t stream) {
    const float* x         = (const float*)d_in[0];  // (B, F)
    const float* fw        = (const float*)d_in[1];  // (T, D, F)
    const float* thr       = (const float*)d_in[2];  // (T, D)
    const float* responses = (const float*)d_in[3];  // (T, L, C)
    float* out             = (float*)d_out;          // (B, C)

    FP* packed = (FP*)d_ws;                          // 16 KB scratch

    node_prep_kernel<<<(T * D) / 4, 256, 0, stream>>>(fw, thr, packed);
    forest_kernel<<<B / 4, 256, 0, stream>>>(x, packed, responses, out);
}

// Round 3
// 103.171 us; speedup vs baseline: 1.2152x; 1.2152x over previous
//
#include <hip/hip_runtime.h>

// Problem constants (from reference)
constexpr int B = 16384;
constexpr int T = 256;
constexpr int D = 8;
constexpr int F = 512;
constexpr int C = 16;
constexpr int L = 256;  // 2^D

struct FP { int fidx; float thr; };  // packed per-(t,d) node info, 8 B

// Kernel 1: per (t,d) argmax over F=512 feature weights, first-occurrence
// tie-break to match jnp.argmax. One wave per row; 4 rows per 256-thread block.
__global__ __launch_bounds__(256) void node_prep_kernel(
    const float* __restrict__ fw,      // (T, D, F)
    const float* __restrict__ thr,     // (T, D)
    FP* __restrict__ packed)           // (T*D)
{
    const int wave = threadIdx.x >> 6;
    const int lane = threadIdx.x & 63;
    const int row  = blockIdx.x * 4 + wave;          // [0, T*D)
    const float* base = fw + (size_t)row * F;

    float best = -INFINITY;
    int bidx = 0;
#pragma unroll
    for (int k = 0; k < F / 64; ++k) {
        const int idx = lane + k * 64;
        const float v = base[idx];
        // within-lane indices strictly increase, so '>' keeps first occurrence
        if (v > best) { best = v; bidx = idx; }
    }
    // 64-lane butterfly reduce; tie-break on smaller index (first occurrence)
#pragma unroll
    for (int off = 32; off >= 1; off >>= 1) {
        const float ov = __shfl_xor(best, off);
        const int   oi = __shfl_xor(bidx, off);
        if (ov > best || (ov == best && oi < bidx)) { best = ov; bidx = oi; }
    }
    if (lane == 0) {
        FP p;
        p.fidx = bidx;
        p.thr  = thr[row];
        packed[row] = p;
    }
}

// Kernel 2: 4 samples per block (4096 blocks, 256 threads).
// Phase 1: stage 4 x-rows (8 KB) in LDS via float4.
// Phase 2: thread t computes decision bytes for tree t for all 4 samples.
// Phase 3: wave w owns sample w. lane = tree-slot(bits 2-5) x channel-quad
//          (bits 0-1). Each lane does 16 independent float4 gathers (named
//          register array -> all in flight), 4 consecutive lanes cover one
//          64 B leaf row. Butterfly reduce over tree-slots; float4 store.
__global__ __launch_bounds__(256, 4) void forest_kernel(
    const float* __restrict__ x,          // (B, F)
    const FP* __restrict__ packed,        // (T*D)
    const float* __restrict__ responses,  // (T, L, C)
    float* __restrict__ out)              // (B, C)
{
    __shared__ float xrow[4][F];             // 8 KB
    __shared__ unsigned char sdec[4][T];     // 1 KB

    const int b0  = blockIdx.x * 4;
    const int tid = threadIdx.x;

    // Phase 1: 4 rows = 2048 floats = 512 float4; 2 per thread, coalesced.
    {
        const float4* xs = reinterpret_cast<const float4*>(x + (size_t)b0 * F);
        float4* xl = reinterpret_cast<float4*>(&xrow[0][0]);
        xl[tid]       = xs[tid];
        xl[tid + 256] = xs[tid + 256];
    }
    __syncthreads();

    // Phase 2: decisions for tree t = tid, samples 0..3.
    {
        const int2* p2 = reinterpret_cast<const int2*>(packed) + tid * D;
        int2 raw[D];
#pragma unroll
        for (int d = 0; d < D; ++d) raw[d] = p2[d];
        int dec0 = 0, dec1 = 0, dec2 = 0, dec3 = 0;
#pragma unroll
        for (int d = 0; d < D; ++d) {
            const int   f  = raw[d].x;
            const float th = __int_as_float(raw[d].y);
            const int   p  = 128 >> d;            // powers = 2^(D-1-d)
            dec0 |= (xrow[0][f] > th) ? p : 0;
            dec1 |= (xrow[1][f] > th) ? p : 0;
            dec2 |= (xrow[2][f] > th) ? p : 0;
            dec3 |= (xrow[3][f] > th) ? p : 0;
        }
        sdec[0][tid] = (unsigned char)dec0;
        sdec[1][tid] = (unsigned char)dec1;
        sdec[2][tid] = (unsigned char)dec2;
        sdec[3][tid] = (unsigned char)dec3;
    }
    __syncthreads();

    // Phase 3: wave w -> sample b0+w.
    const int w    = tid >> 6;
    const int lane = tid & 63;

    // decision words: iter kk needs trees 16kk..16kk+15; lane reads word
    // (lane>>4) of that 16-byte group -> 4 distinct banks, broadcast. Free.
    const int* pw   = reinterpret_cast<const int*>(&sdec[w][0]);
    const int wsel  = lane >> 4;
    const int bsel  = ((lane >> 2) & 3) * 8;      // byte within word = t&3
    int dw[16];
#pragma unroll
    for (int kk = 0; kk < 16; ++kk) dw[kk] = pw[4 * kk + wsel];

    // per-lane constant part of the float offset:
    // off = kk<<16 | (lane>>2)<<12 | dd<<4 | (lane&3)<<2
    const int lbase = ((lane >> 2) << 12) | ((lane & 3) << 2);

    float4 r[16];
#pragma unroll
    for (int kk = 0; kk < 16; ++kk) {
        const int dd = (dw[kk] >> bsel) & 255;
        r[kk] = *reinterpret_cast<const float4*>(
            responses + (kk << 16) + (dd << 4) + lbase);
    }

    float4 acc = r[0];
#pragma unroll
    for (int kk = 1; kk < 16; ++kk) {
        acc.x += r[kk].x; acc.y += r[kk].y;
        acc.z += r[kk].z; acc.w += r[kk].w;
    }

    // reduce across tree-slot bits (lane bits 2..5)
#pragma unroll
    for (int off = 4; off <= 32; off <<= 1) {
        acc.x += __shfl_xor(acc.x, off);
        acc.y += __shfl_xor(acc.y, off);
        acc.z += __shfl_xor(acc.z, off);
        acc.w += __shfl_xor(acc.w, off);
    }

    if (lane < 4) {
        const float s = 1.0f / T;
        float4 o = make_float4(acc.x * s, acc.y * s, acc.z * s, acc.w * s);
        *reinterpret_cast<float4*>(out + ((size_t)(b0 + w) << 4) + (lane << 2)) = o;
    }
}

extern "C" void kernel_launch(void* const* d_in, const int* in_sizes, int n_in,
                              void* d_out, int out_size, void* d_ws, size_t ws_size,
                              hipStream_t stream) {
    const float* x         = (const float*)d_in[0];  // (B, F)
    const float* fw        = (const float*)d_in[1];  // (T, D, F)
    const float* thr       = (const float*)d_in[2];  // (T, D)
    const float* responses = (const float*)d_in[3];  // (T, L, C)
    float* out             = (float*)d_out;          // (B, C)

    FP* packed = (FP*)d_ws;                          // 16 KB scratch

    node_prep_kernel<<<(T * D) / 4, 256, 0, stream>>>(fw, thr, packed);
    forest_kernel<<<B / 4, 256, 0, stream>>>(x, packed, responses, out);
}